// Round 1
// baseline (1006.458 us; speedup 1.0000x reference)
//
#include <hip/hip_runtime.h>

#define FIN 64
#define HID 256
#define DEMB 128
#define NLAYERS 3

// ---------------- small graph-prep kernels ----------------

__global__ __launch_bounds__(256) void zero_kernel(int* counts, int n, float* pool_sum, int* pool_max) {
    int i = blockIdx.x * 256 + threadIdx.x;
    if (i < n) counts[i] = 0;
    if (i < HID) { pool_sum[i] = 0.0f; pool_max[i] = 0; }
}

__global__ __launch_bounds__(256) void hist_kernel(const int* __restrict__ ei, int E, int* __restrict__ counts) {
    int e = blockIdx.x * 256 + threadIdx.x;
    if (e < E) atomicAdd(&counts[ei[E + e]], 1);
}

__global__ __launch_bounds__(256) void dinv_kernel(const int* __restrict__ counts, float* __restrict__ dinv, int n) {
    int v = blockIdx.x * 256 + threadIdx.x;
    if (v < n) dinv[v] = rsqrtf((float)(counts[v] + 1));   // +1 self-loop, always > 0
}

__global__ __launch_bounds__(256) void scan_partial(const int* __restrict__ counts, int n, int* __restrict__ chunkSums) {
    __shared__ int s[256];
    int t = threadIdx.x, base = blockIdx.x * 1024;
    int sum = 0;
#pragma unroll
    for (int j = 0; j < 4; j++) { int i = base + t * 4 + j; if (i < n) sum += counts[i]; }
    s[t] = sum; __syncthreads();
    for (int off = 128; off > 0; off >>= 1) { if (t < off) s[t] += s[t + off]; __syncthreads(); }
    if (t == 0) chunkSums[blockIdx.x] = s[0];
}

__global__ void scan_sums(int* chunkSums, int nch) {
    if (threadIdx.x == 0 && blockIdx.x == 0) {
        int acc = 0;
        for (int i = 0; i < nch; i++) { int x = chunkSums[i]; chunkSums[i] = acc; acc += x; }
    }
}

__global__ __launch_bounds__(256) void scan_final(const int* __restrict__ counts, int n,
                                                  const int* __restrict__ chunkOff, int* __restrict__ row_ptr) {
    __shared__ int s[256];
    int t = threadIdx.x, base = blockIdx.x * 1024;
    int v[4]; int sum = 0;
#pragma unroll
    for (int j = 0; j < 4; j++) { int i = base + t * 4 + j; v[j] = (i < n) ? counts[i] : 0; sum += v[j]; }
    s[t] = sum; __syncthreads();
    for (int off = 1; off < 256; off <<= 1) {
        int x = (t >= off) ? s[t - off] : 0;
        __syncthreads();
        s[t] += x;
        __syncthreads();
    }
    int run = chunkOff[blockIdx.x] + (s[t] - sum);
#pragma unroll
    for (int j = 0; j < 4; j++) {
        int i = base + t * 4 + j;
        if (i < n) {
            row_ptr[i] = run; run += v[j];
            if (i == n - 1) row_ptr[n] = run;
        }
    }
}

__global__ __launch_bounds__(256) void cursor_init(const int* __restrict__ row_ptr, int* __restrict__ cursor, int n) {
    int v = blockIdx.x * 256 + threadIdx.x;
    if (v < n) cursor[v] = row_ptr[v];
}

__global__ __launch_bounds__(256) void fill_kernel(const int* __restrict__ ei, int E,
                                                   int* __restrict__ cursor, int* __restrict__ adj) {
    int e = blockIdx.x * 256 + threadIdx.x;
    if (e < E) {
        int s = ei[e], d = ei[E + e];
        int p = atomicAdd(&cursor[d], 1);
        adj[p] = s;
    }
}

// ---------------- fp32 tiled GEMM: C = A@B (+bias) (+relu) ----------------
// A [M,K] row-major, B [K,N] row-major, C [M,N]. 64x64 tile, BK=32, 256 thr, 4x4/thread.

template<bool RELU, bool BIAS>
__global__ __launch_bounds__(256) void gemm64(const float* __restrict__ A, const float* __restrict__ B,
                                              const float* __restrict__ bias, float* __restrict__ C,
                                              int M, int N, int K) {
    constexpr int BK = 32;
    __shared__ float As[BK][64 + 1];
    __shared__ float Bs[BK][64 + 4];
    int t = threadIdx.x;
    int brow = blockIdx.x * 64, bcol = blockIdx.y * 64;
    int tm = (t >> 4) * 4, tn = (t & 15) * 4;
    float acc[4][4] = {};

    for (int k0 = 0; k0 < K; k0 += BK) {
        // A tile: 64 rows x BK cols -> As[k][row]
#pragma unroll
        for (int l = 0; l < 2; l++) {
            int lin = t + l * 256;             // float4 index over 512
            int r = lin >> 3, kq = lin & 7;    // BK/4 = 8
            int row = brow + r;
            float4 v = make_float4(0.f, 0.f, 0.f, 0.f);
            if (row < M) v = *(const float4*)(A + (size_t)row * K + k0 + kq * 4);
            As[kq * 4 + 0][r] = v.x; As[kq * 4 + 1][r] = v.y;
            As[kq * 4 + 2][r] = v.z; As[kq * 4 + 3][r] = v.w;
        }
        // B tile: BK rows x 64 cols -> Bs[k][col]
#pragma unroll
        for (int l = 0; l < 2; l++) {
            int lin = t + l * 256;
            int kr = lin >> 4, nq = lin & 15;
            float4 v = *(const float4*)(B + (size_t)(k0 + kr) * N + bcol + nq * 4);
            *(float4*)&Bs[kr][nq * 4] = v;
        }
        __syncthreads();
#pragma unroll
        for (int k = 0; k < BK; k++) {
            float a[4], b[4];
#pragma unroll
            for (int i = 0; i < 4; i++) a[i] = As[k][tm + i];
#pragma unroll
            for (int j = 0; j < 4; j++) b[j] = Bs[k][tn + j];
#pragma unroll
            for (int i = 0; i < 4; i++)
#pragma unroll
                for (int j = 0; j < 4; j++) acc[i][j] = fmaf(a[i], b[j], acc[i][j]);
        }
        __syncthreads();
    }

#pragma unroll
    for (int i = 0; i < 4; i++) {
        int row = brow + tm + i;
        if (row < M) {
            float4 o;
            float bx = BIAS ? bias[bcol + tn + 0] : 0.f;
            float by = BIAS ? bias[bcol + tn + 1] : 0.f;
            float bz = BIAS ? bias[bcol + tn + 2] : 0.f;
            float bw = BIAS ? bias[bcol + tn + 3] : 0.f;
            o.x = acc[i][0] + bx; o.y = acc[i][1] + by;
            o.z = acc[i][2] + bz; o.w = acc[i][3] + bw;
            if (RELU) {
                o.x = fmaxf(o.x, 0.f); o.y = fmaxf(o.y, 0.f);
                o.z = fmaxf(o.z, 0.f); o.w = fmaxf(o.w, 0.f);
            }
            *(float4*)(C + (size_t)row * N + bcol + tn) = o;
        }
    }
}

// ---------------- GCN aggregation: one wave per dst node ----------------
// out[v] = relu( dinv[v] * ( dinv[v]*m[v] + sum_e dinv[src_e]*m[src_e] ) + bias )

__global__ __launch_bounds__(256) void aggregate(const float* __restrict__ m, const int* __restrict__ row_ptr,
                                                 const int* __restrict__ adj, const float* __restrict__ dinv,
                                                 const float* __restrict__ bias, float* __restrict__ out, int n) {
    int v = blockIdx.x * 4 + (threadIdx.x >> 6);
    if (v >= n) return;
    int lane = threadIdx.x & 63;
    float dv = dinv[v];
    float4 mv = *(const float4*)(m + (size_t)v * HID + lane * 4);
    float4 acc = make_float4(dv * mv.x, dv * mv.y, dv * mv.z, dv * mv.w);
    int e = row_ptr[v], end = row_ptr[v + 1];
    for (; e + 2 <= end; e += 2) {
        int s0 = adj[e], s1 = adj[e + 1];
        float w0 = dinv[s0], w1 = dinv[s1];
        float4 m0 = *(const float4*)(m + (size_t)s0 * HID + lane * 4);
        float4 m1 = *(const float4*)(m + (size_t)s1 * HID + lane * 4);
        acc.x = fmaf(w0, m0.x, acc.x); acc.y = fmaf(w0, m0.y, acc.y);
        acc.z = fmaf(w0, m0.z, acc.z); acc.w = fmaf(w0, m0.w, acc.w);
        acc.x = fmaf(w1, m1.x, acc.x); acc.y = fmaf(w1, m1.y, acc.y);
        acc.z = fmaf(w1, m1.z, acc.z); acc.w = fmaf(w1, m1.w, acc.w);
    }
    if (e < end) {
        int s0 = adj[e];
        float w0 = dinv[s0];
        float4 m0 = *(const float4*)(m + (size_t)s0 * HID + lane * 4);
        acc.x = fmaf(w0, m0.x, acc.x); acc.y = fmaf(w0, m0.y, acc.y);
        acc.z = fmaf(w0, m0.z, acc.z); acc.w = fmaf(w0, m0.w, acc.w);
    }
    float4 b = *(const float4*)(bias + lane * 4);
    float4 o;
    o.x = fmaxf(fmaf(dv, acc.x, b.x), 0.f);
    o.y = fmaxf(fmaf(dv, acc.y, b.y), 0.f);
    o.z = fmaxf(fmaf(dv, acc.z, b.z), 0.f);
    o.w = fmaxf(fmaf(dv, acc.w, b.w), 0.f);
    *(float4*)(out + (size_t)v * HID + lane * 4) = o;
}

// ---------------- pooling (mean + max over rows) ----------------

__global__ __launch_bounds__(256) void pool_kernel(const float* __restrict__ h, int n,
                                                   float* __restrict__ pool_sum, int* __restrict__ pool_max) {
    int t = threadIdx.x;  // column
    float s = 0.f, mx = 0.f;  // h >= 0 post-relu
    for (int r = blockIdx.x; r < n; r += gridDim.x) {
        float v = h[(size_t)r * HID + t];
        s += v;
        mx = fmaxf(mx, v);
    }
    atomicAdd(&pool_sum[t], s);
    atomicMax(&pool_max[t], __float_as_int(mx));  // valid: all values >= 0
}

// ---------------- final MLP head (single block) ----------------

__global__ __launch_bounds__(256) void mlp_head(const float* __restrict__ pool_sum, const int* __restrict__ pool_max,
                                                const float* __restrict__ Wp1, const float* __restrict__ bp1,
                                                const float* __restrict__ Wp2, const float* __restrict__ bp2,
                                                float* __restrict__ out, float invn) {
    __shared__ float g[2 * HID];
    __shared__ float hid[HID];
    int t = threadIdx.x;
    g[t] = pool_sum[t] * invn;
    g[HID + t] = __int_as_float(pool_max[t]);
    __syncthreads();
    float acc = bp1[t];
#pragma unroll 8
    for (int j = 0; j < 2 * HID; j++) acc = fmaf(g[j], Wp1[j * HID + t], acc);
    hid[t] = fmaxf(acc, 0.f);
    __syncthreads();
    if (t < DEMB) {
        float a2 = bp2[t];
#pragma unroll 8
        for (int j = 0; j < HID; j++) a2 = fmaf(hid[j], Wp2[j * DEMB + t], a2);
        out[t] = a2;
    }
}

// ---------------- launcher ----------------

extern "C" void kernel_launch(void* const* d_in, const int* in_sizes, int n_in,
                              void* d_out, int out_size, void* d_ws, size_t ws_size,
                              hipStream_t stream) {
    const float* x   = (const float*)d_in[0];
    const int*   ei  = (const int*)d_in[1];
    const float* W1  = (const float*)d_in[2];
    const float* b1  = (const float*)d_in[3];
    const float* W2  = (const float*)d_in[4];
    const float* b2  = (const float*)d_in[5];
    const float* Wc  = (const float*)d_in[6];
    const float* bc  = (const float*)d_in[7];
    const float* Wp1 = (const float*)d_in[8];
    const float* bp1 = (const float*)d_in[9];
    const float* Wp2 = (const float*)d_in[10];
    const float* bp2 = (const float*)d_in[11];
    float* out = (float*)d_out;

    int N = in_sizes[0] / FIN;
    int E = in_sizes[1] / 2;

    // workspace carve (all 16B-aligned given d_ws alignment)
    float* hA      = (float*)d_ws;                       // [N, HID]
    float* tmp     = hA + (size_t)N * HID;               // [N, HID]
    int*   counts  = (int*)(tmp + (size_t)N * HID);      // [N]
    int*   row_ptr = counts + N;                         // [N+1]
    int*   cursor  = row_ptr + (N + 1);                  // [N]
    int*   adj     = cursor + N;                         // [E]
    float* dinvp   = (float*)(adj + E);                  // [N]
    float* pool_sum = dinvp + N;                         // [HID]
    int*   pool_max = (int*)(pool_sum + HID);            // [HID]
    int*   chunkSums = pool_max + HID;                   // [nch]

    int nch = (N + 1023) / 1024;
    int nb256 = (N + 255) / 256;
    int eb256 = (E + 255) / 256;

    zero_kernel<<<nb256, 256, 0, stream>>>(counts, N, pool_sum, pool_max);
    hist_kernel<<<eb256, 256, 0, stream>>>(ei, E, counts);
    dinv_kernel<<<nb256, 256, 0, stream>>>(counts, dinvp, N);
    scan_partial<<<nch, 256, 0, stream>>>(counts, N, chunkSums);
    scan_sums<<<1, 64, 0, stream>>>(chunkSums, nch);
    scan_final<<<nch, 256, 0, stream>>>(counts, N, chunkSums, row_ptr);
    cursor_init<<<nb256, 256, 0, stream>>>(row_ptr, cursor, N);
    fill_kernel<<<eb256, 256, 0, stream>>>(ei, E, cursor, adj);

    dim3 gg((N + 63) / 64, HID / 64);
    // encoder
    gemm64<true, true><<<gg, 256, 0, stream>>>(x, W1, b1, tmp, N, HID, FIN);
    gemm64<false, true><<<gg, 256, 0, stream>>>(tmp, W2, b2, hA, N, HID, HID);
    // GCN layers
    for (int L = 0; L < NLAYERS; L++) {
        gemm64<false, false><<<gg, 256, 0, stream>>>(hA, Wc + (size_t)L * HID * HID, nullptr, tmp, N, HID, HID);
        aggregate<<<(N + 3) / 4, 256, 0, stream>>>(tmp, row_ptr, adj, dinvp, bc + (size_t)L * HID, hA, N);
    }
    // pooling + head
    pool_kernel<<<256, 256, 0, stream>>>(hA, N, pool_sum, pool_max);
    mlp_head<<<1, 256, 0, stream>>>(pool_sum, pool_max, Wp1, bp1, Wp2, bp2, out, 1.0f / (float)N);
}

// Round 2
// 961.667 us; speedup vs baseline: 1.0466x; 1.0466x over previous
//
#include <hip/hip_runtime.h>

#define FIN 64
#define HID 256
#define DEMB 128
#define NLAYERS 3

// ---------------- small graph-prep kernels ----------------

__global__ __launch_bounds__(256) void zero_kernel(int* counts, int n, float* pool_sum, int* pool_max) {
    int i = blockIdx.x * 256 + threadIdx.x;
    if (i < n) counts[i] = 0;
    if (i < HID) { pool_sum[i] = 0.0f; pool_max[i] = 0; }
}

__global__ __launch_bounds__(256) void hist_kernel(const int* __restrict__ ei, int E, int* __restrict__ counts) {
    int e = blockIdx.x * 256 + threadIdx.x;
    if (e < E) atomicAdd(&counts[ei[E + e]], 1);
}

__global__ __launch_bounds__(256) void dinv_kernel(const int* __restrict__ counts, float* __restrict__ dinv, int n) {
    int v = blockIdx.x * 256 + threadIdx.x;
    if (v < n) dinv[v] = rsqrtf((float)(counts[v] + 1));   // +1 self-loop, always > 0
}

__global__ __launch_bounds__(256) void scan_partial(const int* __restrict__ counts, int n, int* __restrict__ chunkSums) {
    __shared__ int s[256];
    int t = threadIdx.x, base = blockIdx.x * 1024;
    int sum = 0;
#pragma unroll
    for (int j = 0; j < 4; j++) { int i = base + t * 4 + j; if (i < n) sum += counts[i]; }
    s[t] = sum; __syncthreads();
    for (int off = 128; off > 0; off >>= 1) { if (t < off) s[t] += s[t + off]; __syncthreads(); }
    if (t == 0) chunkSums[blockIdx.x] = s[0];
}

__global__ void scan_sums(int* chunkSums, int nch) {
    if (threadIdx.x == 0 && blockIdx.x == 0) {
        int acc = 0;
        for (int i = 0; i < nch; i++) { int x = chunkSums[i]; chunkSums[i] = acc; acc += x; }
    }
}

__global__ __launch_bounds__(256) void scan_final(const int* __restrict__ counts, int n,
                                                  const int* __restrict__ chunkOff, int* __restrict__ row_ptr) {
    __shared__ int s[256];
    int t = threadIdx.x, base = blockIdx.x * 1024;
    int v[4]; int sum = 0;
#pragma unroll
    for (int j = 0; j < 4; j++) { int i = base + t * 4 + j; v[j] = (i < n) ? counts[i] : 0; sum += v[j]; }
    s[t] = sum; __syncthreads();
    for (int off = 1; off < 256; off <<= 1) {
        int x = (t >= off) ? s[t - off] : 0;
        __syncthreads();
        s[t] += x;
        __syncthreads();
    }
    int run = chunkOff[blockIdx.x] + (s[t] - sum);
#pragma unroll
    for (int j = 0; j < 4; j++) {
        int i = base + t * 4 + j;
        if (i < n) {
            row_ptr[i] = run; run += v[j];
            if (i == n - 1) row_ptr[n] = run;
        }
    }
}

__global__ __launch_bounds__(256) void cursor_init(const int* __restrict__ row_ptr, int* __restrict__ cursor, int n) {
    int v = blockIdx.x * 256 + threadIdx.x;
    if (v < n) cursor[v] = row_ptr[v];
}

__global__ __launch_bounds__(256) void fill_kernel(const int* __restrict__ ei, int E,
                                                   int* __restrict__ cursor, int* __restrict__ adj) {
    int e = blockIdx.x * 256 + threadIdx.x;
    if (e < E) {
        int s = ei[e], d = ei[E + e];
        int p = atomicAdd(&cursor[d], 1);
        adj[p] = s;
    }
}

// ---------------- fp32 tiled GEMM: C = A@B (+bias) (+relu) ----------------
// 128x128 tile, BK=16, 256 threads, 8x8 per thread (split fragments rows/cols
// {q, q+64} so LDS b128 reads are lane-consecutive, conflict-free).

template<bool RELU, bool BIAS>
__global__ __launch_bounds__(256) void gemm128(const float* __restrict__ A, const float* __restrict__ B,
                                               const float* __restrict__ bias, float* __restrict__ C,
                                               int M, int N, int K) {
    constexpr int BK = 16;
    __shared__ float As[BK][128 + 4];   // [k][row]
    __shared__ float Bs[BK][128 + 4];   // [k][col]
    int t = threadIdx.x;
    int brow = blockIdx.x * 128, bcol = blockIdx.y * 128;
    int tm = (t >> 4) * 4, tn = (t & 15) * 4;
    float acc[8][8] = {};

    for (int k0 = 0; k0 < K; k0 += BK) {
        // A tile: 128 rows x 16 cols -> As[k][row] (transposed stage)
#pragma unroll
        for (int l = 0; l < 2; l++) {
            int lin = t + l * 256;                 // float4 index over 512
            int r = lin >> 2, kq = (lin & 3) * 4;
            int row = brow + r;
            float4 v = make_float4(0.f, 0.f, 0.f, 0.f);
            if (row < M) v = *(const float4*)(A + (size_t)row * K + k0 + kq);
            As[kq + 0][r] = v.x; As[kq + 1][r] = v.y;
            As[kq + 2][r] = v.z; As[kq + 3][r] = v.w;
        }
        // B tile: 16 rows x 128 cols -> Bs[k][col]
#pragma unroll
        for (int l = 0; l < 2; l++) {
            int lin = t + l * 256;
            int kr = lin >> 5, nq = (lin & 31) * 4;
            *(float4*)&Bs[kr][nq] = *(const float4*)(B + (size_t)(k0 + kr) * N + bcol + nq);
        }
        __syncthreads();
#pragma unroll
        for (int k = 0; k < BK; k++) {
            float4 a0 = *(float4*)&As[k][tm];
            float4 a1 = *(float4*)&As[k][tm + 64];
            float4 b0 = *(float4*)&Bs[k][tn];
            float4 b1 = *(float4*)&Bs[k][tn + 64];
            float a[8] = {a0.x, a0.y, a0.z, a0.w, a1.x, a1.y, a1.z, a1.w};
            float b[8] = {b0.x, b0.y, b0.z, b0.w, b1.x, b1.y, b1.z, b1.w};
#pragma unroll
            for (int i = 0; i < 8; i++)
#pragma unroll
                for (int j = 0; j < 8; j++) acc[i][j] = fmaf(a[i], b[j], acc[i][j]);
        }
        __syncthreads();
    }

#pragma unroll
    for (int i = 0; i < 8; i++) {
        int row = brow + ((i < 4) ? (tm + i) : (64 + tm + i - 4));
        if (row < M) {
#pragma unroll
            for (int hf = 0; hf < 2; hf++) {
                int col = bcol + tn + hf * 64;
                float4 o;
                o.x = acc[i][hf * 4 + 0]; o.y = acc[i][hf * 4 + 1];
                o.z = acc[i][hf * 4 + 2]; o.w = acc[i][hf * 4 + 3];
                if (BIAS) {
                    o.x += bias[col + 0]; o.y += bias[col + 1];
                    o.z += bias[col + 2]; o.w += bias[col + 3];
                }
                if (RELU) {
                    o.x = fmaxf(o.x, 0.f); o.y = fmaxf(o.y, 0.f);
                    o.z = fmaxf(o.z, 0.f); o.w = fmaxf(o.w, 0.f);
                }
                *(float4*)(C + (size_t)row * N + col) = o;
            }
        }
    }
}

// ---------------- GCN aggregation: one wave per dst node ----------------
// out[v] = relu( dinv[v] * ( dinv[v]*m[v] + sum_e dinv[src_e]*m[src_e] ) + bias )
// 8-deep edge unroll: 8 independent 64B gathers in flight before the FMA chain.

__global__ __launch_bounds__(256) void aggregate(const float* __restrict__ m, const int* __restrict__ row_ptr,
                                                 const int* __restrict__ adj, const float* __restrict__ dinv,
                                                 const float* __restrict__ bias, float* __restrict__ out, int n) {
    int v = blockIdx.x * 4 + (threadIdx.x >> 6);
    if (v >= n) return;
    int lane = threadIdx.x & 63;
    float dv = dinv[v];
    float4 mv = *(const float4*)(m + (size_t)v * HID + lane * 4);
    float4 acc = make_float4(dv * mv.x, dv * mv.y, dv * mv.z, dv * mv.w);
    int e = row_ptr[v], end = row_ptr[v + 1];

    for (; e + 8 <= end; e += 8) {
        int s[8]; float w[8]; float4 mm[8];
#pragma unroll
        for (int j = 0; j < 8; j++) s[j] = adj[e + j];
#pragma unroll
        for (int j = 0; j < 8; j++) mm[j] = *(const float4*)(m + (size_t)s[j] * HID + lane * 4);
#pragma unroll
        for (int j = 0; j < 8; j++) w[j] = dinv[s[j]];
#pragma unroll
        for (int j = 0; j < 8; j++) {
            acc.x = fmaf(w[j], mm[j].x, acc.x); acc.y = fmaf(w[j], mm[j].y, acc.y);
            acc.z = fmaf(w[j], mm[j].z, acc.z); acc.w = fmaf(w[j], mm[j].w, acc.w);
        }
    }
    for (; e + 2 <= end; e += 2) {
        int s0 = adj[e], s1 = adj[e + 1];
        float w0 = dinv[s0], w1 = dinv[s1];
        float4 m0 = *(const float4*)(m + (size_t)s0 * HID + lane * 4);
        float4 m1 = *(const float4*)(m + (size_t)s1 * HID + lane * 4);
        acc.x = fmaf(w0, m0.x, acc.x); acc.y = fmaf(w0, m0.y, acc.y);
        acc.z = fmaf(w0, m0.z, acc.z); acc.w = fmaf(w0, m0.w, acc.w);
        acc.x = fmaf(w1, m1.x, acc.x); acc.y = fmaf(w1, m1.y, acc.y);
        acc.z = fmaf(w1, m1.z, acc.z); acc.w = fmaf(w1, m1.w, acc.w);
    }
    if (e < end) {
        int s0 = adj[e];
        float w0 = dinv[s0];
        float4 m0 = *(const float4*)(m + (size_t)s0 * HID + lane * 4);
        acc.x = fmaf(w0, m0.x, acc.x); acc.y = fmaf(w0, m0.y, acc.y);
        acc.z = fmaf(w0, m0.z, acc.z); acc.w = fmaf(w0, m0.w, acc.w);
    }
    float4 b = *(const float4*)(bias + lane * 4);
    float4 o;
    o.x = fmaxf(fmaf(dv, acc.x, b.x), 0.f);
    o.y = fmaxf(fmaf(dv, acc.y, b.y), 0.f);
    o.z = fmaxf(fmaf(dv, acc.z, b.z), 0.f);
    o.w = fmaxf(fmaf(dv, acc.w, b.w), 0.f);
    *(float4*)(out + (size_t)v * HID + lane * 4) = o;
}

// ---------------- pooling (mean + max over rows) ----------------

__global__ __launch_bounds__(256) void pool_kernel(const float* __restrict__ h, int n,
                                                   float* __restrict__ pool_sum, int* __restrict__ pool_max) {
    int t = threadIdx.x;  // column
    float s = 0.f, mx = 0.f;  // h >= 0 post-relu
    for (int r = blockIdx.x; r < n; r += gridDim.x) {
        float v = h[(size_t)r * HID + t];
        s += v;
        mx = fmaxf(mx, v);
    }
    atomicAdd(&pool_sum[t], s);
    atomicMax(&pool_max[t], __float_as_int(mx));  // valid: all values >= 0
}

// ---------------- final MLP head (single block) ----------------

__global__ __launch_bounds__(256) void mlp_head(const float* __restrict__ pool_sum, const int* __restrict__ pool_max,
                                                const float* __restrict__ Wp1, const float* __restrict__ bp1,
                                                const float* __restrict__ Wp2, const float* __restrict__ bp2,
                                                float* __restrict__ out, float invn) {
    __shared__ float g[2 * HID];
    __shared__ float hid[HID];
    int t = threadIdx.x;
    g[t] = pool_sum[t] * invn;
    g[HID + t] = __int_as_float(pool_max[t]);
    __syncthreads();
    float acc = bp1[t];
#pragma unroll 8
    for (int j = 0; j < 2 * HID; j++) acc = fmaf(g[j], Wp1[j * HID + t], acc);
    hid[t] = fmaxf(acc, 0.f);
    __syncthreads();
    if (t < DEMB) {
        float a2 = bp2[t];
#pragma unroll 8
        for (int j = 0; j < HID; j++) a2 = fmaf(hid[j], Wp2[j * DEMB + t], a2);
        out[t] = a2;
    }
}

// ---------------- launcher ----------------

extern "C" void kernel_launch(void* const* d_in, const int* in_sizes, int n_in,
                              void* d_out, int out_size, void* d_ws, size_t ws_size,
                              hipStream_t stream) {
    const float* x   = (const float*)d_in[0];
    const int*   ei  = (const int*)d_in[1];
    const float* W1  = (const float*)d_in[2];
    const float* b1  = (const float*)d_in[3];
    const float* W2  = (const float*)d_in[4];
    const float* b2  = (const float*)d_in[5];
    const float* Wc  = (const float*)d_in[6];
    const float* bc  = (const float*)d_in[7];
    const float* Wp1 = (const float*)d_in[8];
    const float* bp1 = (const float*)d_in[9];
    const float* Wp2 = (const float*)d_in[10];
    const float* bp2 = (const float*)d_in[11];
    float* out = (float*)d_out;

    int N = in_sizes[0] / FIN;
    int E = in_sizes[1] / 2;

    // workspace carve (all 16B-aligned given d_ws alignment)
    float* hA      = (float*)d_ws;                       // [N, HID]
    float* tmp     = hA + (size_t)N * HID;               // [N, HID]
    int*   counts  = (int*)(tmp + (size_t)N * HID);      // [N]
    int*   row_ptr = counts + N;                         // [N+1]
    int*   cursor  = row_ptr + (N + 1);                  // [N]
    int*   adj     = cursor + N;                         // [E]
    float* dinvp   = (float*)(adj + E);                  // [N]
    float* pool_sum = dinvp + N;                         // [HID]
    int*   pool_max = (int*)(pool_sum + HID);            // [HID]
    int*   chunkSums = pool_max + HID;                   // [nch]

    int nch = (N + 1023) / 1024;
    int nb256 = (N + 255) / 256;
    int eb256 = (E + 255) / 256;

    zero_kernel<<<nb256, 256, 0, stream>>>(counts, N, pool_sum, pool_max);
    hist_kernel<<<eb256, 256, 0, stream>>>(ei, E, counts);
    dinv_kernel<<<nb256, 256, 0, stream>>>(counts, dinvp, N);
    scan_partial<<<nch, 256, 0, stream>>>(counts, N, chunkSums);
    scan_sums<<<1, 64, 0, stream>>>(chunkSums, nch);
    scan_final<<<nch, 256, 0, stream>>>(counts, N, chunkSums, row_ptr);
    cursor_init<<<nb256, 256, 0, stream>>>(row_ptr, cursor, N);
    fill_kernel<<<eb256, 256, 0, stream>>>(ei, E, cursor, adj);

    dim3 gg((N + 127) / 128, HID / 128);
    // encoder
    gemm128<true, true><<<gg, 256, 0, stream>>>(x, W1, b1, tmp, N, HID, FIN);
    gemm128<false, true><<<gg, 256, 0, stream>>>(tmp, W2, b2, hA, N, HID, HID);
    // GCN layers
    for (int L = 0; L < NLAYERS; L++) {
        gemm128<false, false><<<gg, 256, 0, stream>>>(hA, Wc + (size_t)L * HID * HID, nullptr, tmp, N, HID, HID);
        aggregate<<<(N + 3) / 4, 256, 0, stream>>>(tmp, row_ptr, adj, dinvp, bc + (size_t)L * HID, hA, N);
    }
    // pooling + head
    pool_kernel<<<256, 256, 0, stream>>>(hA, N, pool_sum, pool_max);
    mlp_head<<<1, 256, 0, stream>>>(pool_sum, pool_max, Wp1, bp1, Wp2, bp2, out, 1.0f / (float)N);
}

// Round 3
// 743.289 us; speedup vs baseline: 1.3541x; 1.2938x over previous
//
#include <hip/hip_runtime.h>

#define FIN 64
#define HID 256
#define DEMB 128
#define NLAYERS 3

typedef __attribute__((ext_vector_type(8))) short bf16x8;
typedef __attribute__((ext_vector_type(4))) float f32x4;

__device__ inline short f2bf(float x) {               // RNE fp32 -> bf16 bits
    unsigned u = __float_as_uint(x);
    u += 0x7fff + ((u >> 16) & 1);
    return (short)(u >> 16);
}
__device__ inline float bf2f(short h) {
    return __uint_as_float(((unsigned)(unsigned short)h) << 16);
}

// ---------------- small graph-prep kernels ----------------

__global__ __launch_bounds__(256) void zero_kernel(int* counts, int n, float* pool_sum, int* pool_max) {
    int i = blockIdx.x * 256 + threadIdx.x;
    if (i < n) counts[i] = 0;
    if (i < HID) { pool_sum[i] = 0.0f; pool_max[i] = 0; }
}

__global__ __launch_bounds__(256) void hist_kernel(const int* __restrict__ ei, int E, int* __restrict__ counts) {
    int e = blockIdx.x * 256 + threadIdx.x;
    if (e < E) atomicAdd(&counts[ei[E + e]], 1);
}

__global__ __launch_bounds__(256) void dinv_kernel(const int* __restrict__ counts, float* __restrict__ dinv, int n) {
    int v = blockIdx.x * 256 + threadIdx.x;
    if (v < n) dinv[v] = rsqrtf((float)(counts[v] + 1));   // +1 self-loop, always > 0
}

__global__ __launch_bounds__(256) void scan_partial(const int* __restrict__ counts, int n, int* __restrict__ chunkSums) {
    __shared__ int s[256];
    int t = threadIdx.x, base = blockIdx.x * 1024;
    int sum = 0;
#pragma unroll
    for (int j = 0; j < 4; j++) { int i = base + t * 4 + j; if (i < n) sum += counts[i]; }
    s[t] = sum; __syncthreads();
    for (int off = 128; off > 0; off >>= 1) { if (t < off) s[t] += s[t + off]; __syncthreads(); }
    if (t == 0) chunkSums[blockIdx.x] = s[0];
}

__global__ void scan_sums(int* chunkSums, int nch) {
    if (threadIdx.x == 0 && blockIdx.x == 0) {
        int acc = 0;
        for (int i = 0; i < nch; i++) { int x = chunkSums[i]; chunkSums[i] = acc; acc += x; }
    }
}

__global__ __launch_bounds__(256) void scan_final(const int* __restrict__ counts, int n,
                                                  const int* __restrict__ chunkOff, int* __restrict__ row_ptr) {
    __shared__ int s[256];
    int t = threadIdx.x, base = blockIdx.x * 1024;
    int v[4]; int sum = 0;
#pragma unroll
    for (int j = 0; j < 4; j++) { int i = base + t * 4 + j; v[j] = (i < n) ? counts[i] : 0; sum += v[j]; }
    s[t] = sum; __syncthreads();
    for (int off = 1; off < 256; off <<= 1) {
        int x = (t >= off) ? s[t - off] : 0;
        __syncthreads();
        s[t] += x;
        __syncthreads();
    }
    int run = chunkOff[blockIdx.x] + (s[t] - sum);
#pragma unroll
    for (int j = 0; j < 4; j++) {
        int i = base + t * 4 + j;
        if (i < n) {
            row_ptr[i] = run; run += v[j];
            if (i == n - 1) row_ptr[n] = run;
        }
    }
}

__global__ __launch_bounds__(256) void cursor_init(const int* __restrict__ row_ptr, int* __restrict__ cursor, int n) {
    int v = blockIdx.x * 256 + threadIdx.x;
    if (v < n) cursor[v] = row_ptr[v];
}

__global__ __launch_bounds__(256) void fill_kernel(const int* __restrict__ ei, int E,
                                                   int* __restrict__ cursor, int* __restrict__ adj) {
    int e = blockIdx.x * 256 + threadIdx.x;
    if (e < E) {
        int s = ei[e], d = ei[E + e];
        int p = atomicAdd(&cursor[d], 1);
        adj[p] = s;
    }
}

// ---------------- weight packing: fp32 [K][256] -> split-bf16 fragment order ----
// element k,n -> Ph/Pl[ ((s*4+g)*256 + n)*8 + i ],  k = s*32 + g*8 + i

__global__ __launch_bounds__(256) void pack_w(const float* __restrict__ W, short* __restrict__ Ph,
                                              short* __restrict__ Pl, int K) {
    int idx = blockIdx.x * 256 + threadIdx.x;
    if (idx >= K * 256) return;
    int k = idx >> 8, n = idx & 255;
    float w = W[idx];
    short h = f2bf(w);
    short l = f2bf(w - bf2f(h));
    int s = k >> 5, g = (k >> 3) & 3, i = k & 7;
    int o = (((s * 4 + g) << 8) + n) * 8 + i;
    Ph[o] = h; Pl[o] = l;
}

// ---------------- split-bf16 MFMA GEMM: C[M,256] = A[M,K] @ B + bias ----------
// BM=64, BN=256 (full), 4 waves (wave w -> cols [64w,64w+64)), BK=32.
// A LDS-staged + converted in-kernel; B fragments read directly from packed
// global (L2-resident). 3-term split: AhBh + AhBl + AlBh, fp32 accum.

template<bool RELU, bool BIAS, int K>
__global__ __launch_bounds__(256) void gemm_mfma(const float* __restrict__ A,
                                                 const short* __restrict__ PBh, const short* __restrict__ PBl,
                                                 const float* __restrict__ bias, float* __restrict__ C, int M) {
    __shared__ short AhL[4][64][8];   // [g][row][i] : k = g*8+i within step
    __shared__ short AlL[4][64][8];
    int t = threadIdx.x;
    int lane = t & 63, wave = t >> 6;
    int brow = blockIdx.x * 64;
    int bcol = wave * 64;
    int lr = lane & 15, lg = lane >> 4;
    f32x4 acc[4][4] = {};

    constexpr int NS = K / 32;
    float4 a_pre[2];
#pragma unroll
    for (int l = 0; l < 2; l++) {
        int lin = t + l * 256;
        int r = lin >> 3, kq = (lin & 7) * 4;
        int row = brow + r;
        a_pre[l] = (row < M) ? *(const float4*)(A + (size_t)row * K + kq)
                             : make_float4(0.f, 0.f, 0.f, 0.f);
    }

    for (int s = 0; s < NS; ++s) {
        // convert + LDS-write A for step s
#pragma unroll
        for (int l = 0; l < 2; l++) {
            int lin = t + l * 256;
            int r = lin >> 3, kq = (lin & 7) * 4;
            int g = kq >> 3, i0 = kq & 7;
            float4 v = a_pre[l];
            short h0 = f2bf(v.x), h1 = f2bf(v.y), h2 = f2bf(v.z), h3 = f2bf(v.w);
            short e0 = f2bf(v.x - bf2f(h0)), e1 = f2bf(v.y - bf2f(h1));
            short e2 = f2bf(v.z - bf2f(h2)), e3 = f2bf(v.w - bf2f(h3));
            uint2 hw, lw;
            hw.x = (unsigned short)h0 | ((unsigned)(unsigned short)h1 << 16);
            hw.y = (unsigned short)h2 | ((unsigned)(unsigned short)h3 << 16);
            lw.x = (unsigned short)e0 | ((unsigned)(unsigned short)e1 << 16);
            lw.y = (unsigned short)e2 | ((unsigned)(unsigned short)e3 << 16);
            *(uint2*)&AhL[g][r][i0] = hw;
            *(uint2*)&AlL[g][r][i0] = lw;
        }
        // B fragments for step s: straight from packed global (L2)
        const short* pbh = PBh + ((size_t)(s * 4 + lg) * 256 + bcol + lr) * 8;
        const short* pbl = PBl + ((size_t)(s * 4 + lg) * 256 + bcol + lr) * 8;
        bf16x8 bh[4], bl[4];
#pragma unroll
        for (int ni = 0; ni < 4; ni++) {
            bh[ni] = *(const bf16x8*)(pbh + ni * 128);
            bl[ni] = *(const bf16x8*)(pbl + ni * 128);
        }
        // prefetch next A step into regs
        if (s + 1 < NS) {
#pragma unroll
            for (int l = 0; l < 2; l++) {
                int lin = t + l * 256;
                int r = lin >> 3, kq = (lin & 7) * 4;
                int row = brow + r;
                a_pre[l] = (row < M) ? *(const float4*)(A + (size_t)row * K + (s + 1) * 32 + kq)
                                     : make_float4(0.f, 0.f, 0.f, 0.f);
            }
        }
        __syncthreads();
        bf16x8 ah[4], al[4];
#pragma unroll
        for (int mi = 0; mi < 4; mi++) {
            ah[mi] = *(bf16x8*)&AhL[lg][mi * 16 + lr][0];
            al[mi] = *(bf16x8*)&AlL[lg][mi * 16 + lr][0];
        }
#pragma unroll
        for (int mi = 0; mi < 4; mi++)
#pragma unroll
            for (int ni = 0; ni < 4; ni++) {
                acc[mi][ni] = __builtin_amdgcn_mfma_f32_16x16x32_bf16(ah[mi], bh[ni], acc[mi][ni], 0, 0, 0);
                acc[mi][ni] = __builtin_amdgcn_mfma_f32_16x16x32_bf16(ah[mi], bl[ni], acc[mi][ni], 0, 0, 0);
                acc[mi][ni] = __builtin_amdgcn_mfma_f32_16x16x32_bf16(al[mi], bh[ni], acc[mi][ni], 0, 0, 0);
            }
        if (s + 1 < NS) __syncthreads();
    }

    // epilogue: C row = brow + mi*16 + lg*4 + j, col = bcol + ni*16 + lr
#pragma unroll
    for (int ni = 0; ni < 4; ni++) {
        int col = bcol + ni * 16 + lr;
        float bv = BIAS ? bias[col] : 0.f;
#pragma unroll
        for (int mi = 0; mi < 4; mi++)
#pragma unroll
            for (int j = 0; j < 4; j++) {
                int row = brow + mi * 16 + lg * 4 + j;
                if (row < M) {
                    float o = acc[mi][ni][j] + bv;
                    if (RELU) o = fmaxf(o, 0.f);
                    C[(size_t)row * 256 + col] = o;
                }
            }
    }
}

// ---------------- GCN aggregation: one wave per dst node ----------------

__global__ __launch_bounds__(256) void aggregate(const float* __restrict__ m, const int* __restrict__ row_ptr,
                                                 const int* __restrict__ adj, const float* __restrict__ dinv,
                                                 const float* __restrict__ bias, float* __restrict__ out, int n) {
    int v = blockIdx.x * 4 + (threadIdx.x >> 6);
    if (v >= n) return;
    int lane = threadIdx.x & 63;
    float dv = dinv[v];
    float4 mv = *(const float4*)(m + (size_t)v * HID + lane * 4);
    float4 acc = make_float4(dv * mv.x, dv * mv.y, dv * mv.z, dv * mv.w);
    int e = row_ptr[v], end = row_ptr[v + 1];

    for (; e + 8 <= end; e += 8) {
        int s[8]; float w[8]; float4 mm[8];
#pragma unroll
        for (int j = 0; j < 8; j++) s[j] = adj[e + j];
#pragma unroll
        for (int j = 0; j < 8; j++) mm[j] = *(const float4*)(m + (size_t)s[j] * HID + lane * 4);
#pragma unroll
        for (int j = 0; j < 8; j++) w[j] = dinv[s[j]];
#pragma unroll
        for (int j = 0; j < 8; j++) {
            acc.x = fmaf(w[j], mm[j].x, acc.x); acc.y = fmaf(w[j], mm[j].y, acc.y);
            acc.z = fmaf(w[j], mm[j].z, acc.z); acc.w = fmaf(w[j], mm[j].w, acc.w);
        }
    }
    for (; e < end; e++) {
        int s0 = adj[e];
        float w0 = dinv[s0];
        float4 m0 = *(const float4*)(m + (size_t)s0 * HID + lane * 4);
        acc.x = fmaf(w0, m0.x, acc.x); acc.y = fmaf(w0, m0.y, acc.y);
        acc.z = fmaf(w0, m0.z, acc.z); acc.w = fmaf(w0, m0.w, acc.w);
    }
    float4 b = *(const float4*)(bias + lane * 4);
    float4 o;
    o.x = fmaxf(fmaf(dv, acc.x, b.x), 0.f);
    o.y = fmaxf(fmaf(dv, acc.y, b.y), 0.f);
    o.z = fmaxf(fmaf(dv, acc.z, b.z), 0.f);
    o.w = fmaxf(fmaf(dv, acc.w, b.w), 0.f);
    *(float4*)(out + (size_t)v * HID + lane * 4) = o;
}

// ---------------- pooling (mean + max over rows) ----------------

__global__ __launch_bounds__(256) void pool_kernel(const float* __restrict__ h, int n,
                                                   float* __restrict__ pool_sum, int* __restrict__ pool_max) {
    int t = threadIdx.x;  // column
    float s = 0.f, mx = 0.f;  // h >= 0 post-relu
    for (int r = blockIdx.x; r < n; r += gridDim.x) {
        float v = h[(size_t)r * HID + t];
        s += v;
        mx = fmaxf(mx, v);
    }
    atomicAdd(&pool_sum[t], s);
    atomicMax(&pool_max[t], __float_as_int(mx));  // valid: all values >= 0
}

// ---------------- final MLP head (single block) ----------------

__global__ __launch_bounds__(256) void mlp_head(const float* __restrict__ pool_sum, const int* __restrict__ pool_max,
                                                const float* __restrict__ Wp1, const float* __restrict__ bp1,
                                                const float* __restrict__ Wp2, const float* __restrict__ bp2,
                                                float* __restrict__ out, float invn) {
    __shared__ float g[2 * HID];
    __shared__ float hid[HID];
    int t = threadIdx.x;
    g[t] = pool_sum[t] * invn;
    g[HID + t] = __int_as_float(pool_max[t]);
    __syncthreads();
    float acc = bp1[t];
#pragma unroll 8
    for (int j = 0; j < 2 * HID; j++) acc = fmaf(g[j], Wp1[j * HID + t], acc);
    hid[t] = fmaxf(acc, 0.f);
    __syncthreads();
    if (t < DEMB) {
        float a2 = bp2[t];
#pragma unroll 8
        for (int j = 0; j < HID; j++) a2 = fmaf(hid[j], Wp2[j * DEMB + t], a2);
        out[t] = a2;
    }
}

// ---------------- launcher ----------------

extern "C" void kernel_launch(void* const* d_in, const int* in_sizes, int n_in,
                              void* d_out, int out_size, void* d_ws, size_t ws_size,
                              hipStream_t stream) {
    const float* x   = (const float*)d_in[0];
    const int*   ei  = (const int*)d_in[1];
    const float* W1  = (const float*)d_in[2];
    const float* b1  = (const float*)d_in[3];
    const float* W2  = (const float*)d_in[4];
    const float* b2  = (const float*)d_in[5];
    const float* Wc  = (const float*)d_in[6];
    const float* bc  = (const float*)d_in[7];
    const float* Wp1 = (const float*)d_in[8];
    const float* bp1 = (const float*)d_in[9];
    const float* Wp2 = (const float*)d_in[10];
    const float* bp2 = (const float*)d_in[11];
    float* out = (float*)d_out;

    int N = in_sizes[0] / FIN;
    int E = in_sizes[1] / 2;

    // workspace carve
    float* hA      = (float*)d_ws;                       // [N, HID]
    float* tmp     = hA + (size_t)N * HID;               // [N, HID]
    int*   counts  = (int*)(tmp + (size_t)N * HID);      // [N]
    int*   row_ptr = counts + N;                         // [N+1]
    int*   cursor  = row_ptr + (N + 1);                  // [N]
    int*   adj     = cursor + N;                         // [E]
    float* dinvp   = (float*)(adj + E);                  // [N]
    float* pool_sum = dinvp + N;                         // [HID]
    int*   pool_max = (int*)(pool_sum + HID);            // [HID]
    int*   chunkSums = pool_max + HID;                   // [<=256]
    // packed split-bf16 weights (16B aligned)
    short* PH = (short*)((((uintptr_t)(chunkSums + 256)) + 15) & ~(uintptr_t)15);
    short* PL = PH + 278528;
    // per-matrix offsets (in elements): W1, W2, Wc0, Wc1, Wc2
    const int oW1 = 0, oW2 = 16384, oC0 = 81920, oC1 = 147456, oC2 = 212992;

    int nch = (N + 1023) / 1024;
    int nb256 = (N + 255) / 256;
    int eb256 = (E + 255) / 256;

    zero_kernel<<<nb256, 256, 0, stream>>>(counts, N, pool_sum, pool_max);
    hist_kernel<<<eb256, 256, 0, stream>>>(ei, E, counts);
    dinv_kernel<<<nb256, 256, 0, stream>>>(counts, dinvp, N);
    scan_partial<<<nch, 256, 0, stream>>>(counts, N, chunkSums);
    scan_sums<<<1, 64, 0, stream>>>(chunkSums, nch);
    scan_final<<<nch, 256, 0, stream>>>(counts, N, chunkSums, row_ptr);
    cursor_init<<<nb256, 256, 0, stream>>>(row_ptr, cursor, N);
    fill_kernel<<<eb256, 256, 0, stream>>>(ei, E, cursor, adj);

    // pack weights (fragment-ordered split bf16)
    pack_w<<<FIN, 256, 0, stream>>>(W1, PH + oW1, PL + oW1, FIN);
    pack_w<<<HID, 256, 0, stream>>>(W2, PH + oW2, PL + oW2, HID);
    pack_w<<<HID, 256, 0, stream>>>(Wc + 0 * HID * HID, PH + oC0, PL + oC0, HID);
    pack_w<<<HID, 256, 0, stream>>>(Wc + 1 * HID * HID, PH + oC1, PL + oC1, HID);
    pack_w<<<HID, 256, 0, stream>>>(Wc + 2 * HID * HID, PH + oC2, PL + oC2, HID);

    int gb = (N + 63) / 64;
    // encoder
    gemm_mfma<true, true, FIN><<<gb, 256, 0, stream>>>(x, PH + oW1, PL + oW1, b1, tmp, N);
    gemm_mfma<false, true, HID><<<gb, 256, 0, stream>>>(tmp, PH + oW2, PL + oW2, b2, hA, N);
    // GCN layers
    const int oC[3] = {oC0, oC1, oC2};
    for (int L = 0; L < NLAYERS; L++) {
        gemm_mfma<false, false, HID><<<gb, 256, 0, stream>>>(hA, PH + oC[L], PL + oC[L], nullptr, tmp, N);
        aggregate<<<(N + 3) / 4, 256, 0, stream>>>(tmp, row_ptr, adj, dinvp, bc + (size_t)L * HID, hA, N);
    }
    // pooling + head
    pool_kernel<<<256, 256, 0, stream>>>(hA, N, pool_sum, pool_max);
    mlp_head<<<1, 256, 0, stream>>>(pool_sum, pool_max, Wp1, bp1, Wp2, bp2, out, 1.0f / (float)N);
}

// Round 4
// 741.229 us; speedup vs baseline: 1.3578x; 1.0028x over previous
//
#include <hip/hip_runtime.h>

#define FIN 64
#define HID 256
#define DEMB 128
#define NLAYERS 3

typedef __attribute__((ext_vector_type(8))) short bf16x8;
typedef __attribute__((ext_vector_type(4))) float f32x4;

__device__ inline short f2bf(float x) {               // RNE fp32 -> bf16 bits
    unsigned u = __float_as_uint(x);
    u += 0x7fff + ((u >> 16) & 1);
    return (short)(u >> 16);
}
__device__ inline float bf2f(short h) {
    return __uint_as_float(((unsigned)(unsigned short)h) << 16);
}

// ---------------- small graph-prep kernels ----------------

__global__ __launch_bounds__(256) void zero_kernel(int* counts, int n, float* pool_sum, int* pool_max) {
    int i = blockIdx.x * 256 + threadIdx.x;
    if (i < n) counts[i] = 0;
    if (i < HID) { pool_sum[i] = 0.0f; pool_max[i] = 0; }
}

__global__ __launch_bounds__(256) void hist_kernel(const int* __restrict__ ei, int E, int* __restrict__ counts) {
    int e = blockIdx.x * 256 + threadIdx.x;
    if (e < E) atomicAdd(&counts[ei[E + e]], 1);
}

__global__ __launch_bounds__(256) void dinv_kernel(const int* __restrict__ counts, float* __restrict__ dinv, int n) {
    int v = blockIdx.x * 256 + threadIdx.x;
    if (v < n) dinv[v] = rsqrtf((float)(counts[v] + 1));   // +1 self-loop, always > 0
}

__global__ __launch_bounds__(256) void scan_partial(const int* __restrict__ counts, int n, int* __restrict__ chunkSums) {
    __shared__ int s[256];
    int t = threadIdx.x, base = blockIdx.x * 1024;
    int sum = 0;
#pragma unroll
    for (int j = 0; j < 4; j++) { int i = base + t * 4 + j; if (i < n) sum += counts[i]; }
    s[t] = sum; __syncthreads();
    for (int off = 128; off > 0; off >>= 1) { if (t < off) s[t] += s[t + off]; __syncthreads(); }
    if (t == 0) chunkSums[blockIdx.x] = s[0];
}

// wave-parallel exclusive scan over <=64 chunk sums
__global__ void scan_sums(int* cs, int nch) {
    int l = threadIdx.x;          // 64 threads
    int orig = (l < nch) ? cs[l] : 0;
    int v = orig;
    for (int off = 1; off < 64; off <<= 1) {
        int x = __shfl_up(v, off, 64);
        if (l >= off) v += x;
    }
    if (l < nch) cs[l] = v - orig;   // exclusive
}

__global__ __launch_bounds__(256) void scan_final(const int* __restrict__ counts, int n,
                                                  const int* __restrict__ chunkOff, int* __restrict__ row_ptr) {
    __shared__ int s[256];
    int t = threadIdx.x, base = blockIdx.x * 1024;
    int v[4]; int sum = 0;
#pragma unroll
    for (int j = 0; j < 4; j++) { int i = base + t * 4 + j; v[j] = (i < n) ? counts[i] : 0; sum += v[j]; }
    s[t] = sum; __syncthreads();
    for (int off = 1; off < 256; off <<= 1) {
        int x = (t >= off) ? s[t - off] : 0;
        __syncthreads();
        s[t] += x;
        __syncthreads();
    }
    int run = chunkOff[blockIdx.x] + (s[t] - sum);
#pragma unroll
    for (int j = 0; j < 4; j++) {
        int i = base + t * 4 + j;
        if (i < n) {
            row_ptr[i] = run; run += v[j];
            if (i == n - 1) row_ptr[n] = run;
        }
    }
}

__global__ __launch_bounds__(256) void cursor_init(const int* __restrict__ row_ptr, int* __restrict__ cursor, int n) {
    int v = blockIdx.x * 256 + threadIdx.x;
    if (v < n) cursor[v] = row_ptr[v];
}

__global__ __launch_bounds__(256) void fill_kernel(const int* __restrict__ ei, int E,
                                                   int* __restrict__ cursor, int* __restrict__ adj) {
    int e = blockIdx.x * 256 + threadIdx.x;
    if (e < E) {
        int s = ei[e], d = ei[E + e];
        int p = atomicAdd(&cursor[d], 1);
        adj[p] = s;
    }
}

// ---------------- weight packing: all 5 matrices in one launch ----------------
// element (k,n) -> P[ ((k>>3)*256 + n)*8 + (k&7) ]  (slab = s*4+g = k>>3)

__global__ __launch_bounds__(256) void pack_all(const float* __restrict__ W1, const float* __restrict__ W2,
                                                const float* __restrict__ Wc,
                                                short* __restrict__ PH, short* __restrict__ PL) {
    int b = blockIdx.x, n = threadIdx.x;
    const float* src; int k; size_t dst;
    if (b < 64) { src = W1; k = b; dst = 0; }
    else {
        int m = (b - 64) >> 8; k = (b - 64) & 255;
        src = (m == 0) ? W2 : (Wc + (size_t)(m - 1) * 65536);
        dst = 16384 + (size_t)m * 65536;
    }
    float w = src[(size_t)k * 256 + n];
    short h = f2bf(w);
    short l = f2bf(w - bf2f(h));
    int o = ((k >> 3) * 256 + n) * 8 + (k & 7);
    PH[dst + o] = h; PL[dst + o] = l;
}

// ---------------- split-bf16 MFMA GEMM, fp32 A (convert in kernel) ------------
// BM=64, BN=256, 4 waves, BK=32. OUTP: write packed split-bf16 activation.

template<int K, bool RELU, bool BIAS, bool OUTP>
__global__ __launch_bounds__(256) void gemm_conv(const float* __restrict__ A,
                                                 const short* __restrict__ PBh, const short* __restrict__ PBl,
                                                 const float* __restrict__ bias,
                                                 float* __restrict__ Cf, short* __restrict__ Cp,
                                                 int M, int R) {
    __shared__ short AhL[4][64][8];   // [g][row][i] : k = g*8+i within step
    __shared__ short AlL[4][64][8];
    int t = threadIdx.x;
    int lane = t & 63, wave = t >> 6;
    int brow = blockIdx.x * 64;
    int bcol = wave * 64;
    int lr = lane & 15, lg = lane >> 4;
    f32x4 acc[4][4] = {};

    constexpr int NS = K / 32;
    float4 a_pre[2];
#pragma unroll
    for (int l = 0; l < 2; l++) {
        int lin = t + l * 256;
        int r = lin >> 3, kq = (lin & 7) * 4;
        int row = brow + r;
        a_pre[l] = (row < M) ? *(const float4*)(A + (size_t)row * K + kq)
                             : make_float4(0.f, 0.f, 0.f, 0.f);
    }

    for (int s = 0; s < NS; ++s) {
#pragma unroll
        for (int l = 0; l < 2; l++) {
            int lin = t + l * 256;
            int r = lin >> 3, kq = (lin & 7) * 4;
            int g = kq >> 3, i0 = kq & 7;
            float4 v = a_pre[l];
            short h0 = f2bf(v.x), h1 = f2bf(v.y), h2 = f2bf(v.z), h3 = f2bf(v.w);
            short e0 = f2bf(v.x - bf2f(h0)), e1 = f2bf(v.y - bf2f(h1));
            short e2 = f2bf(v.z - bf2f(h2)), e3 = f2bf(v.w - bf2f(h3));
            uint2 hw, lw;
            hw.x = (unsigned short)h0 | ((unsigned)(unsigned short)h1 << 16);
            hw.y = (unsigned short)h2 | ((unsigned)(unsigned short)h3 << 16);
            lw.x = (unsigned short)e0 | ((unsigned)(unsigned short)e1 << 16);
            lw.y = (unsigned short)e2 | ((unsigned)(unsigned short)e3 << 16);
            *(uint2*)&AhL[g][r][i0] = hw;
            *(uint2*)&AlL[g][r][i0] = lw;
        }
        const short* pbh = PBh + ((size_t)(s * 4 + lg) * 256 + bcol + lr) * 8;
        const short* pbl = PBl + ((size_t)(s * 4 + lg) * 256 + bcol + lr) * 8;
        bf16x8 bh[4], bl[4];
#pragma unroll
        for (int ni = 0; ni < 4; ni++) {
            bh[ni] = *(const bf16x8*)(pbh + ni * 128);
            bl[ni] = *(const bf16x8*)(pbl + ni * 128);
        }
        if (s + 1 < NS) {
#pragma unroll
            for (int l = 0; l < 2; l++) {
                int lin = t + l * 256;
                int r = lin >> 3, kq = (lin & 7) * 4;
                int row = brow + r;
                a_pre[l] = (row < M) ? *(const float4*)(A + (size_t)row * K + (s + 1) * 32 + kq)
                                     : make_float4(0.f, 0.f, 0.f, 0.f);
            }
        }
        __syncthreads();
        bf16x8 ah[4], al[4];
#pragma unroll
        for (int mi = 0; mi < 4; mi++) {
            ah[mi] = *(bf16x8*)&AhL[lg][mi * 16 + lr][0];
            al[mi] = *(bf16x8*)&AlL[lg][mi * 16 + lr][0];
        }
#pragma unroll
        for (int mi = 0; mi < 4; mi++)
#pragma unroll
            for (int ni = 0; ni < 4; ni++) {
                acc[mi][ni] = __builtin_amdgcn_mfma_f32_16x16x32_bf16(ah[mi], bh[ni], acc[mi][ni], 0, 0, 0);
                acc[mi][ni] = __builtin_amdgcn_mfma_f32_16x16x32_bf16(ah[mi], bl[ni], acc[mi][ni], 0, 0, 0);
                acc[mi][ni] = __builtin_amdgcn_mfma_f32_16x16x32_bf16(al[mi], bh[ni], acc[mi][ni], 0, 0, 0);
            }
        if (s + 1 < NS) __syncthreads();
    }

    short* Cpl = OUTP ? (Cp + (size_t)R * 256) : nullptr;
#pragma unroll
    for (int ni = 0; ni < 4; ni++) {
        int col = bcol + ni * 16 + lr;
        float bv = BIAS ? bias[col] : 0.f;
#pragma unroll
        for (int mi = 0; mi < 4; mi++)
#pragma unroll
            for (int j = 0; j < 4; j++) {
                int row = brow + mi * 16 + lg * 4 + j;
                if (row < M) {
                    float o = acc[mi][ni][j] + bv;
                    if (RELU) o = fmaxf(o, 0.f);
                    if (OUTP) {
                        short hh = f2bf(o);
                        short hl = f2bf(o - bf2f(hh));
                        size_t off = ((size_t)(col >> 3) * R + row) * 8 + (col & 7);
                        Cp[off] = hh; Cpl[off] = hl;
                    } else {
                        Cf[(size_t)row * 256 + col] = o;
                    }
                }
            }
    }
}

// ---------------- pure-MFMA GEMM, packed split-bf16 A (no LDS, no barriers) ----
// C[M,256] = A @ B, A packed fragment-order, out fp32 row-major.

__global__ __launch_bounds__(256) void gemm_packedA(const short* __restrict__ APh,
                                                    const short* __restrict__ PBh, const short* __restrict__ PBl,
                                                    float* __restrict__ C, int M, int R) {
    int t = threadIdx.x;
    int lane = t & 63, wave = t >> 6;
    int brow = blockIdx.x * 64;
    int bcol = wave * 64;
    int lr = lane & 15, lg = lane >> 4;
    const short* APl = APh + (size_t)R * 256;
    f32x4 acc[4][4] = {};

#pragma unroll
    for (int s = 0; s < 8; ++s) {
        size_t abase = ((size_t)(s * 4 + lg) * R + brow + lr) * 8;
        bf16x8 ah[4], al[4], bh[4], bl[4];
#pragma unroll
        for (int mi = 0; mi < 4; mi++) {
            ah[mi] = *(const bf16x8*)(APh + abase + mi * 128);
            al[mi] = *(const bf16x8*)(APl + abase + mi * 128);
        }
        const short* pbh = PBh + ((size_t)(s * 4 + lg) * 256 + bcol + lr) * 8;
        const short* pbl = PBl + ((size_t)(s * 4 + lg) * 256 + bcol + lr) * 8;
#pragma unroll
        for (int ni = 0; ni < 4; ni++) {
            bh[ni] = *(const bf16x8*)(pbh + ni * 128);
            bl[ni] = *(const bf16x8*)(pbl + ni * 128);
        }
#pragma unroll
        for (int mi = 0; mi < 4; mi++)
#pragma unroll
            for (int ni = 0; ni < 4; ni++) {
                acc[mi][ni] = __builtin_amdgcn_mfma_f32_16x16x32_bf16(ah[mi], bh[ni], acc[mi][ni], 0, 0, 0);
                acc[mi][ni] = __builtin_amdgcn_mfma_f32_16x16x32_bf16(ah[mi], bl[ni], acc[mi][ni], 0, 0, 0);
                acc[mi][ni] = __builtin_amdgcn_mfma_f32_16x16x32_bf16(al[mi], bh[ni], acc[mi][ni], 0, 0, 0);
            }
    }

#pragma unroll
    for (int ni = 0; ni < 4; ni++) {
        int col = bcol + ni * 16 + lr;
#pragma unroll
        for (int mi = 0; mi < 4; mi++)
#pragma unroll
            for (int j = 0; j < 4; j++) {
                int row = brow + mi * 16 + lg * 4 + j;
                if (row < M) C[(size_t)row * 256 + col] = acc[mi][ni][j];
            }
    }
}

// ---------------- GCN aggregation: one wave per dst node, packed output -------
// out[v] = relu( dv * ( dv*m[v] + sum_e dinv[src]*m[src] ) + bias ) -> split-bf16 packed

__global__ __launch_bounds__(256) void aggregate(const float* __restrict__ m, const int* __restrict__ row_ptr,
                                                 const int* __restrict__ adj, const float* __restrict__ dinv,
                                                 const float* __restrict__ bias,
                                                 short* __restrict__ outPh, int n, int R) {
    int v = blockIdx.x * 4 + (threadIdx.x >> 6);
    if (v >= n) return;
    int lane = threadIdx.x & 63;
    float dv = dinv[v];
    float4 mv = *(const float4*)(m + (size_t)v * HID + lane * 4);
    float4 acc = make_float4(dv * mv.x, dv * mv.y, dv * mv.z, dv * mv.w);
    int e = row_ptr[v], end = row_ptr[v + 1];

    for (; e + 8 <= end; e += 8) {
        int s[8]; float w[8]; float4 mm[8];
#pragma unroll
        for (int j = 0; j < 8; j++) s[j] = adj[e + j];
#pragma unroll
        for (int j = 0; j < 8; j++) mm[j] = *(const float4*)(m + (size_t)s[j] * HID + lane * 4);
#pragma unroll
        for (int j = 0; j < 8; j++) w[j] = dinv[s[j]];
#pragma unroll
        for (int j = 0; j < 8; j++) {
            acc.x = fmaf(w[j], mm[j].x, acc.x); acc.y = fmaf(w[j], mm[j].y, acc.y);
            acc.z = fmaf(w[j], mm[j].z, acc.z); acc.w = fmaf(w[j], mm[j].w, acc.w);
        }
    }
    for (; e < end; e++) {
        int s0 = adj[e];
        float w0 = dinv[s0];
        float4 m0 = *(const float4*)(m + (size_t)s0 * HID + lane * 4);
        acc.x = fmaf(w0, m0.x, acc.x); acc.y = fmaf(w0, m0.y, acc.y);
        acc.z = fmaf(w0, m0.z, acc.z); acc.w = fmaf(w0, m0.w, acc.w);
    }
    float4 b = *(const float4*)(bias + lane * 4);
    float4 o;
    o.x = fmaxf(fmaf(dv, acc.x, b.x), 0.f);
    o.y = fmaxf(fmaf(dv, acc.y, b.y), 0.f);
    o.z = fmaxf(fmaf(dv, acc.z, b.z), 0.f);
    o.w = fmaxf(fmaf(dv, acc.w, b.w), 0.f);

    // pack split-bf16: cols c = lane*4 + j -> slab = lane>>1, i0 = (lane&1)*4
    short h0 = f2bf(o.x), h1 = f2bf(o.y), h2 = f2bf(o.z), h3 = f2bf(o.w);
    short l0 = f2bf(o.x - bf2f(h0)), l1 = f2bf(o.y - bf2f(h1));
    short l2 = f2bf(o.z - bf2f(h2)), l3 = f2bf(o.w - bf2f(h3));
    uint2 hw, lw;
    hw.x = (unsigned short)h0 | ((unsigned)(unsigned short)h1 << 16);
    hw.y = (unsigned short)h2 | ((unsigned)(unsigned short)h3 << 16);
    lw.x = (unsigned short)l0 | ((unsigned)(unsigned short)l1 << 16);
    lw.y = (unsigned short)l2 | ((unsigned)(unsigned short)l3 << 16);
    size_t off = ((size_t)(lane >> 1) * R + v) * 8 + (lane & 1) * 4;
    *(uint2*)(outPh + off) = hw;
    *(uint2*)(outPh + (size_t)R * 256 + off) = lw;
}

// ---------------- pooling (mean + max over rows) from packed h ----------------

__global__ __launch_bounds__(256) void pool_packed(const short* __restrict__ Ph, int n, int R,
                                                   float* __restrict__ pool_sum, int* __restrict__ pool_max) {
    int t = threadIdx.x;  // column
    const short* Pl = Ph + (size_t)R * 256;
    size_t base = (size_t)(t >> 3) * R * 8 + (t & 7);
    int chunk = (n + gridDim.x - 1) / gridDim.x;
    int r0 = blockIdx.x * chunk, r1 = min(n, r0 + chunk);
    float s = 0.f, mx = 0.f;  // h >= 0 post-relu
    for (int r = r0; r < r1; r++) {
        size_t a = base + (size_t)r * 8;
        float v = bf2f(Ph[a]) + bf2f(Pl[a]);
        s += v;
        mx = fmaxf(mx, v);
    }
    atomicAdd(&pool_sum[t], s);
    atomicMax(&pool_max[t], __float_as_int(mx));  // valid: all values >= 0
}

// ---------------- final MLP head (single block) ----------------

__global__ __launch_bounds__(256) void mlp_head(const float* __restrict__ pool_sum, const int* __restrict__ pool_max,
                                                const float* __restrict__ Wp1, const float* __restrict__ bp1,
                                                const float* __restrict__ Wp2, const float* __restrict__ bp2,
                                                float* __restrict__ out, float invn) {
    __shared__ float g[2 * HID];
    __shared__ float hid[HID];
    int t = threadIdx.x;
    g[t] = pool_sum[t] * invn;
    g[HID + t] = __int_as_float(pool_max[t]);
    __syncthreads();
    float acc = bp1[t];
#pragma unroll 8
    for (int j = 0; j < 2 * HID; j++) acc = fmaf(g[j], Wp1[j * HID + t], acc);
    hid[t] = fmaxf(acc, 0.f);
    __syncthreads();
    if (t < DEMB) {
        float a2 = bp2[t];
#pragma unroll 8
        for (int j = 0; j < HID; j++) a2 = fmaf(hid[j], Wp2[j * DEMB + t], a2);
        out[t] = a2;
    }
}

// ---------------- launcher ----------------

extern "C" void kernel_launch(void* const* d_in, const int* in_sizes, int n_in,
                              void* d_out, int out_size, void* d_ws, size_t ws_size,
                              hipStream_t stream) {
    const float* x   = (const float*)d_in[0];
    const int*   ei  = (const int*)d_in[1];
    const float* W1  = (const float*)d_in[2];
    const float* b1  = (const float*)d_in[3];
    const float* W2  = (const float*)d_in[4];
    const float* b2  = (const float*)d_in[5];
    const float* Wc  = (const float*)d_in[6];
    const float* bc  = (const float*)d_in[7];
    const float* Wp1 = (const float*)d_in[8];
    const float* bp1 = (const float*)d_in[9];
    const float* Wp2 = (const float*)d_in[10];
    const float* bp2 = (const float*)d_in[11];
    float* out = (float*)d_out;

    int N = in_sizes[0] / FIN;
    int E = in_sizes[1] / 2;
    int gb = (N + 63) / 64;
    int R  = gb * 64;                    // padded row count for packed activations

    // workspace carve
    float* tmp     = (float*)d_ws;                       // [N, 256] fp32 (aggregate input)
    short* actPh   = (short*)(tmp + (size_t)N * HID);    // [R*256]*2 shorts (Ph+Pl packed act)
    int*   counts  = (int*)(actPh + (size_t)R * 256 * 2);// [N]
    int*   row_ptr = counts + N;                         // [N+1]
    int*   cursor  = row_ptr + (N + 1);                  // [N]
    int*   adj     = cursor + N;                         // [E]
    float* dinvp   = (float*)(adj + E);                  // [N]
    float* pool_sum = dinvp + N;                         // [HID]
    int*   pool_max = (int*)(pool_sum + HID);            // [HID]
    int*   chunkSums = pool_max + HID;                   // [<=64]
    short* PH = (short*)((((uintptr_t)(chunkSums + 64)) + 15) & ~(uintptr_t)15);
    short* PL = PH + 278528;
    const int oW1 = 0, oW2 = 16384, oC0 = 81920, oC1 = 147456, oC2 = 212992;

    int nch = (N + 1023) / 1024;
    int nb256 = (N + 255) / 256;
    int eb256 = (E + 255) / 256;

    zero_kernel<<<nb256, 256, 0, stream>>>(counts, N, pool_sum, pool_max);
    hist_kernel<<<eb256, 256, 0, stream>>>(ei, E, counts);
    dinv_kernel<<<nb256, 256, 0, stream>>>(counts, dinvp, N);
    scan_partial<<<nch, 256, 0, stream>>>(counts, N, chunkSums);
    scan_sums<<<1, 64, 0, stream>>>(chunkSums, nch);
    scan_final<<<nch, 256, 0, stream>>>(counts, N, chunkSums, row_ptr);
    cursor_init<<<nb256, 256, 0, stream>>>(row_ptr, cursor, N);
    fill_kernel<<<eb256, 256, 0, stream>>>(ei, E, cursor, adj);

    pack_all<<<64 + 4 * 256, 256, 0, stream>>>(W1, W2, Wc, PH, PL);

    // encoder: tmp = relu(x@W1+b1) [fp32 out]; actP = tmp@W2+b2 [packed out]
    gemm_conv<FIN, true, true, false><<<gb, 256, 0, stream>>>(x, PH + oW1, PL + oW1, b1, tmp, nullptr, N, R);
    gemm_conv<HID, false, true, true><<<gb, 256, 0, stream>>>(tmp, PH + oW2, PL + oW2, b2, nullptr, actPh, N, R);

    // GCN layers: tmp = actP@Wc (pure MFMA), actP = agg(tmp) packed
    const int oC[3] = {oC0, oC1, oC2};
    for (int L = 0; L < NLAYERS; L++) {
        gemm_packedA<<<gb, 256, 0, stream>>>(actPh, PH + oC[L], PL + oC[L], tmp, N, R);
        aggregate<<<(N + 3) / 4, 256, 0, stream>>>(tmp, row_ptr, adj, dinvp, bc + (size_t)L * HID, actPh, N, R);
    }

    // pooling + head
    pool_packed<<<256, 256, 0, stream>>>(actPh, N, R, pool_sum, pool_max);
    mlp_head<<<1, 256, 0, stream>>>(pool_sum, pool_max, Wp1, bp1, Wp2, bp2, out, 1.0f / (float)N);
}